// Round 3
// baseline (455.966 us; speedup 1.0000x reference)
//
#include <hip/hip_runtime.h>
#include <math.h>

#define T_LEN    16000
#define T_LEN4   4000          // float4 count per row
#define THREADS  256
#define CHUNK    16            // 64B contiguous per thread -> direct float4 ld/st
#define TILE4    (THREADS * 4) // 1024 float4 = 4096 floats per tile
#define NT       4             // 4*4096 = 16384 >= 16000; tail = 3712 = 232*16 (chunk-aligned)
#define EPS_F    1e-6f

// No bulk LDS at all: input and output move directly between registers and HBM
// (per-thread 64B-contiguous chunks, 16B-aligned). Only cross-thread traffic is
// the 4-float wave-partial exchange -> 64B LDS, 1 barrier per tile (parity-
// double-buffered swA/swB makes the WAR hazard 2 barriers away).
// Occupancy: VGPR-bound only. launch_bounds(256,6) -> VGPR<=84, 6 blocks/CU,
// 24 waves/CU (1.5x the previous LDS-staged version).
__launch_bounds__(THREADS, 6)
__global__ void pcen_kernel(const float* __restrict__ x,
                            const float* __restrict__ alpha,
                            const float* __restrict__ delta,
                            const float* __restrict__ root,
                            const float* __restrict__ ema_w,
                            float* __restrict__ out, int C) {
    __shared__ float swA[2][4], swB[2][4];

    const int row  = blockIdx.x;
    const int c    = row % C;
    const int tid  = threadIdx.x;
    const int lane = tid & 63;
    const int wave = tid >> 6;

    const float s   = fminf(fmaxf(ema_w[c], 0.0f), 1.0f);
    const float q   = 1.0f - s;
    const float a_c = fminf(alpha[c], 1.0f);
    const float r   = 1.0f / fmaxf(root[c], 1.0f);
    const float d   = delta[c];
    const float dr  = powf(d, r);
    const float q16 = powf(q, (float)CHUNK);   // composed A over a full chunk
    const bool  sqrt_path = (r == 0.5f);       // root=2 -> (v+d)^r is a sqrt

    const float4* x4 = (const float4*)(x   + (size_t)row * T_LEN);
    float4*       o4 = (float4*)      (out + (size_t)row * T_LEN);

    float e_carry = 0.0f;

    for (int t = 0; t < NT; ++t) {
        const int  base4 = t * TILE4 + tid * 4;      // this thread's first float4
        const bool valid = (base4 < T_LEN4);         // all-or-nothing per chunk
        const int  p     = t & 1;                    // swA/swB parity

        // ---- load own chunk: 4x global_load_dwordx4, no LDS, no barrier ----
        float4 v0, v1, v2, v3;
        if (valid) {
            v0 = x4[base4 + 0]; v1 = x4[base4 + 1];
            v2 = x4[base4 + 2]; v3 = x4[base4 + 3];
        } else {
            v0 = v1 = v2 = v3 = make_float4(1.f, 1.f, 1.f, 1.f);
        }
        float xv[CHUNK] = { v0.x, v0.y, v0.z, v0.w,  v1.x, v1.y, v1.z, v1.w,
                            v2.x, v2.y, v2.z, v2.w,  v3.x, v3.y, v3.z, v3.w };

        // ---- pass 1: compose (A,b) over the 16-element chunk ----
        const bool ft = (t == 0) && (tid == 0);      // owns the very first element
        float la = ft ? 0.0f  : q16;                 // A = 0*q^15 or q^16
        float lb = ft ? xv[0] : s * xv[0];
        #pragma unroll
        for (int j = 1; j < CHUNK; ++j) lb = fmaf(q, lb, s * xv[j]);

        // ---- wave-level inclusive scan (Hillis-Steele, 64 lanes) ----
        #pragma unroll
        for (int off = 1; off < 64; off <<= 1) {
            float ua = __shfl_up(la, off);
            float ub = __shfl_up(lb, off);
            if (lane >= off) { lb = fmaf(la, ub, lb); la *= ua; }
        }
        if (lane == 63) { swA[p][wave] = la; swB[p][wave] = lb; }
        __syncthreads();   // the ONLY barrier per tile

        // ---- wave-exclusive prefix pair ----
        float pa = 1.0f, pb = 0.0f;
        #pragma unroll
        for (int w = 0; w < 3; ++w)
            if (w < wave) { pb = fmaf(swA[p][w], pb, swB[p][w]); pa *= swA[p][w]; }

        // ---- thread-exclusive prefix within wave ----
        float ea = __shfl_up(la, 1);
        float eb = __shfl_up(lb, 1);
        float a_ex, b_ex;
        if (lane == 0) { a_ex = pa;      b_ex = pb; }
        else           { a_ex = pa * ea; b_ex = fmaf(ea, pb, eb); }
        float e = fmaf(a_ex, e_carry, b_ex);   // EMA state entering this chunk

        // ---- tile-total -> carry for next tile (uniform across threads) ----
        float ta = 1.0f, tb = 0.0f;
        #pragma unroll
        for (int w = 0; w < 4; ++w) { tb = fmaf(swA[p][w], tb, swB[p][w]); ta *= swA[p][w]; }
        e_carry = fmaf(ta, e_carry, tb);

        // ---- pass 2: EMA recurrence + pointwise, in registers; store direct ----
        if (valid) {
            if (sqrt_path) {
                #pragma unroll
                for (int j = 0; j < CHUNK; ++j) {
                    float xvj = xv[j];
                    e = (ft && j == 0) ? xvj : fmaf(q, e, s * xvj);
                    float lge = log2f(EPS_F + e);
                    float v   = xvj * exp2f(-a_c * lge);
                    xv[j] = sqrtf(v + d) - dr;
                }
            } else {
                #pragma unroll
                for (int j = 0; j < CHUNK; ++j) {
                    float xvj = xv[j];
                    e = (ft && j == 0) ? xvj : fmaf(q, e, s * xvj);
                    float lge = log2f(EPS_F + e);
                    float v   = xvj * exp2f(-a_c * lge);
                    xv[j] = exp2f(r * log2f(v + d)) - dr;
                }
            }
            o4[base4 + 0] = make_float4(xv[ 0], xv[ 1], xv[ 2], xv[ 3]);
            o4[base4 + 1] = make_float4(xv[ 4], xv[ 5], xv[ 6], xv[ 7]);
            o4[base4 + 2] = make_float4(xv[ 8], xv[ 9], xv[10], xv[11]);
            o4[base4 + 3] = make_float4(xv[12], xv[13], xv[14], xv[15]);
        }
        // swA/swB WAR safety: tile t+1 writes the other parity; the next write to
        // THIS parity (tile t+2) is after barrier(t+1), while all reads of it
        // precede barrier(t+1) in program order. One barrier per tile suffices.
    }
}

extern "C" void kernel_launch(void* const* d_in, const int* in_sizes, int n_in,
                              void* d_out, int out_size, void* d_ws, size_t ws_size,
                              hipStream_t stream) {
    const float* x     = (const float*)d_in[0];
    const float* alpha = (const float*)d_in[1];
    const float* delta = (const float*)d_in[2];
    const float* root  = (const float*)d_in[3];
    const float* ema_w = (const float*)d_in[4];
    float* out = (float*)d_out;

    const int C    = in_sizes[1];               // 128
    const int rows = in_sizes[0] / T_LEN;       // B*C = 4096

    pcen_kernel<<<rows, THREADS, 0, stream>>>(x, alpha, delta, root, ema_w, out, C);
}

// Round 4
// 449.129 us; speedup vs baseline: 1.0152x; 1.0152x over previous
//
#include <hip/hip_runtime.h>
#include <math.h>

#define T_LEN    16000
#define T_LEN4   4000          // float4 count per row
#define THREADS  256
#define CHUNK    16            // 64B contiguous per thread -> direct float4 ld/st
#define TILE4    (THREADS * 4) // 1024 float4 = 4096 floats per tile
#define NT       4             // 4*4096 = 16384 >= 16000; tail 3712 = 232*16 (chunk-aligned)
#define EPS_F    1e-6f

// Zero bulk LDS; per-thread 64B-contiguous chunks move directly reg<->HBM.
// KEY CHANGE vs R3: __syncthreads() drains vmcnt(0) (documented hipcc behavior),
// which killed all cross-tile load/store pipelining. The barrier here only
// protects the 64B swA/swB exchange -> raw s_barrier + lgkmcnt(0)-only wait.
// Prefetched global loads and output stores now stay in flight ACROSS barriers
// (counted-vmcnt pipeline, T4). 4 tiles fully unrolled, two named reg sets.
__launch_bounds__(THREADS, 5)   // VGPR <= 102 (est ~80 live), 20 waves/CU
__global__ void pcen_kernel(const float* __restrict__ x,
                            const float* __restrict__ alpha,
                            const float* __restrict__ delta,
                            const float* __restrict__ root,
                            const float* __restrict__ ema_w,
                            float* __restrict__ out, int C) {
    __shared__ float swA[2][4], swB[2][4];

    const int row  = blockIdx.x;
    const int c    = row % C;
    const int tid  = threadIdx.x;
    const int lane = tid & 63;
    const int wave = tid >> 6;

    const float s   = fminf(fmaxf(ema_w[c], 0.0f), 1.0f);
    const float q   = 1.0f - s;
    const float a_c = fminf(alpha[c], 1.0f);
    const float r   = 1.0f / fmaxf(root[c], 1.0f);
    const float d   = delta[c];
    const float dr  = powf(d, r);
    const float q16 = powf(q, (float)CHUNK);   // composed A over a full chunk
    const bool  sqrt_path = (r == 0.5f);       // root=2 -> (v+d)^r is a sqrt

    const float4* x4 = (const float4*)(x   + (size_t)row * T_LEN);
    float4*       o4 = (float4*)      (out + (size_t)row * T_LEN);

    float e_carry = 0.0f;

    auto loadt = [&](int t, float4& r0, float4& r1, float4& r2, float4& r3) {
        const int b = t * TILE4 + tid * 4;
        if (b < T_LEN4) { r0 = x4[b]; r1 = x4[b+1]; r2 = x4[b+2]; r3 = x4[b+3]; }
        else            { r0 = r1 = r2 = r3 = make_float4(1.f, 1.f, 1.f, 1.f); }
    };

    auto body = [&](int t, float4& c0, float4& c1, float4& c2, float4& c3,
                    bool pref, float4& n0, float4& n1, float4& n2, float4& n3) {
        const int  base4 = t * TILE4 + tid * 4;
        const bool valid = (base4 < T_LEN4);     // all-or-nothing per chunk
        const int  p     = t & 1;                // swA/swB parity

        float xv[CHUNK] = { c0.x, c0.y, c0.z, c0.w,  c1.x, c1.y, c1.z, c1.w,
                            c2.x, c2.y, c2.z, c2.w,  c3.x, c3.y, c3.z, c3.w };

        // ---- prefetch next tile NOW; stays in flight across the barrier ----
        if (pref) loadt(t + 1, n0, n1, n2, n3);

        // ---- pass 1: compose (A,b) over the 16-element chunk ----
        const bool ft = (t == 0) && (tid == 0);  // owns the very first element
        float la = ft ? 0.0f  : q16;             // A = 0*q^15 or q^16
        float lb = ft ? xv[0] : s * xv[0];
        #pragma unroll
        for (int j = 1; j < CHUNK; ++j) lb = fmaf(q, lb, s * xv[j]);

        // ---- wave-level inclusive scan (Hillis-Steele, 64 lanes) ----
        #pragma unroll
        for (int off = 1; off < 64; off <<= 1) {
            float ua = __shfl_up(la, off);
            float ub = __shfl_up(lb, off);
            if (lane >= off) { lb = fmaf(la, ub, lb); la *= ua; }
        }
        if (lane == 63) { swA[p][wave] = la; swB[p][wave] = lb; }

        // ---- barrier WITHOUT vmcnt drain: LDS-only wait + raw s_barrier ----
        asm volatile("s_waitcnt lgkmcnt(0)" ::: "memory");
        __builtin_amdgcn_s_barrier();

        // ---- wave-exclusive prefix pair ----
        float pa = 1.0f, pb = 0.0f;
        #pragma unroll
        for (int w = 0; w < 3; ++w)
            if (w < wave) { pb = fmaf(swA[p][w], pb, swB[p][w]); pa *= swA[p][w]; }

        // ---- thread-exclusive prefix within wave ----
        float ea = __shfl_up(la, 1);
        float eb = __shfl_up(lb, 1);
        float a_ex, b_ex;
        if (lane == 0) { a_ex = pa;      b_ex = pb; }
        else           { a_ex = pa * ea; b_ex = fmaf(ea, pb, eb); }
        float e = fmaf(a_ex, e_carry, b_ex);     // EMA state entering this chunk

        // ---- tile-total -> carry for next tile (uniform across threads) ----
        float ta = 1.0f, tb = 0.0f;
        #pragma unroll
        for (int w = 0; w < 4; ++w) { tb = fmaf(swA[p][w], tb, swB[p][w]); ta *= swA[p][w]; }
        e_carry = fmaf(ta, e_carry, tb);

        // ---- pass 2: EMA recurrence + pointwise in registers; store direct ----
        if (valid) {
            if (sqrt_path) {
                #pragma unroll
                for (int j = 0; j < CHUNK; ++j) {
                    float xvj = xv[j];
                    e = (ft && j == 0) ? xvj : fmaf(q, e, s * xvj);
                    float lge = log2f(EPS_F + e);
                    float v   = xvj * exp2f(-a_c * lge);
                    xv[j] = sqrtf(v + d) - dr;
                }
            } else {
                #pragma unroll
                for (int j = 0; j < CHUNK; ++j) {
                    float xvj = xv[j];
                    e = (ft && j == 0) ? xvj : fmaf(q, e, s * xvj);
                    float lge = log2f(EPS_F + e);
                    float v   = xvj * exp2f(-a_c * lge);
                    xv[j] = exp2f(r * log2f(v + d)) - dr;
                }
            }
            o4[base4 + 0] = make_float4(xv[ 0], xv[ 1], xv[ 2], xv[ 3]);
            o4[base4 + 1] = make_float4(xv[ 4], xv[ 5], xv[ 6], xv[ 7]);
            o4[base4 + 2] = make_float4(xv[ 8], xv[ 9], xv[10], xv[11]);
            o4[base4 + 3] = make_float4(xv[12], xv[13], xv[14], xv[15]);
        }
        // swA/swB WAR safety: parity p is rewritten at tile t+2, which is after
        // barrier(t+1); all reads of parity p precede barrier(t+1) in program
        // order and their lgkm waits are forced before use. One barrier/tile.
    };

    float4 a0, a1, a2, a3, b0, b1, b2, b3;
    loadt(0, a0, a1, a2, a3);
    body(0, a0, a1, a2, a3, true,  b0, b1, b2, b3);
    body(1, b0, b1, b2, b3, true,  a0, a1, a2, a3);
    body(2, a0, a1, a2, a3, true,  b0, b1, b2, b3);
    body(3, b0, b1, b2, b3, false, a0, a1, a2, a3);
}

extern "C" void kernel_launch(void* const* d_in, const int* in_sizes, int n_in,
                              void* d_out, int out_size, void* d_ws, size_t ws_size,
                              hipStream_t stream) {
    const float* x     = (const float*)d_in[0];
    const float* alpha = (const float*)d_in[1];
    const float* delta = (const float*)d_in[2];
    const float* root  = (const float*)d_in[3];
    const float* ema_w = (const float*)d_in[4];
    float* out = (float*)d_out;

    const int C    = in_sizes[1];               // 128
    const int rows = in_sizes[0] / T_LEN;       // B*C = 4096

    pcen_kernel<<<rows, THREADS, 0, stream>>>(x, alpha, delta, root, ema_w, out, C);
}